// Round 5
// baseline (4442.417 us; speedup 1.0000x reference)
//
#include <hip/hip_runtime.h>

typedef _Float16 h16;
typedef h16 h16x8 __attribute__((ext_vector_type(8)));
typedef float f32x4 __attribute__((ext_vector_type(4)));

#define MFMA16(a, b, c) __builtin_amdgcn_mfma_f32_16x16x32_f16(a, b, c, 0, 0, 0)
#define SFENCE __builtin_amdgcn_sched_barrier(0)

typedef __attribute__((address_space(1))) const char gconst_char;
typedef __attribute__((address_space(3))) char lds_char;
#define GL_LDS16(g, l) __builtin_amdgcn_global_load_lds((gconst_char*)(g), (lds_char*)(l), 16, 0, 0)

// ---------------- workspace layout (bytes) ----------------
// Fragment-major fp16 weight blocks: B-fragment f of a chunk at chunk_base + f*1024 + lane*16.
#define WIN_CSH   16384                    // [frag 16][lane 64][16B], 8 chunks
#define WIN_OFF   0
#define WUP_CSH   16384                    // 32 chunks
#define WUP_OFF   131072
#define WDN_CSH   16384                    // 32 chunks
#define WDN_OFF   655360
#define WCOMB_CSH 32768                    // [frag 32][lane 64][16B], 8 chunks
#define WCOMB_OFF 1179648
#define WYT_CSH   16384                    // 8 chunks
#define WYT_OFF   1441792
#define WHEAD_SZ  8192                     // [frag 8][lane 64][16B]
#define WHEAD_OFF 1572864
#define ZY_OFF    1581056
#define ZY_BYTES  (131072UL * 512UL * 2UL) // [B][512] halfs: z cols 0..255, y cols 256..511

// ---------------- mega kernel LDS (8 waves x 32 rows) ----------------
#define L_WUP0 0
#define L_WUP1 16384
#define L_WDN0 32768
#define L_WDN1 49152
#define L_HS   65536        // + wave*2688 : [32][42] halfs per wave (chunk Hs + transposes)
#define L_BUP  87040        // f32[1024]
#define L_BDN  91136        // f32[256]
#define L_LNW  92160
#define L_LNB  93184
#define SMEM_MEGA 94208     // 1 block/CU

// ---------------- comb kernel LDS (8 waves x 16 rows) ----------------
#define C_WC0 0
#define C_WC1 32768
#define C_WY0 65536
#define C_WY1 81920
#define C_GS  98304         // + wave*1344
#define C_BC  109056        // f32[256]
#define C_BY  110080
#define SMEM_COMB 111104

#define SMEM_HEAD 8192

#define SLICE_W 42          // halfs; stride 21 dwords coprime with 32 banks -> conflict-free

__device__ __forceinline__ void stage_calls(const char* src, char* dst, int calls, int wave,
                                            int nw, int lane) {
  for (int i = wave; i < calls; i += nw)
    GL_LDS16(src + i * 1024 + lane * 16, dst + i * 1024);
}

__device__ __forceinline__ float gelu_f(float x) {
  float t = x * (1.5957691216f + 0.0713548354f * x * x);
  float e = __expf(-t);
  return x * __builtin_amdgcn_rcpf(1.0f + e);
}

// ================= prep kernels: fp32 -> fp16 fragment-major blocks =================
__global__ void prepC_kernel(const float* __restrict__ src, h16* __restrict__ dst,
                             int Nsrc, int CSHh, int tot) {
  for (int d = blockIdx.x * 256 + threadIdx.x; d < tot; d += gridDim.x * 256) {
    int chunk = d / CSHh, r = d % CSHh;
    int frag = r >> 9, lane = (r >> 3) & 63, j = r & 7;
    int kk = frag >> 1, nt = frag & 1, q = lane >> 4, c = lane & 15;
    int k = kk * 32 + q * 8 + j;
    int n = chunk * 32 + nt * 16 + c;
    dst[d] = (h16)src[(long)k * Nsrc + n];
  }
}
__global__ void prepD_kernel(const float* __restrict__ src, h16* __restrict__ dst, int tot) {
  for (int d = blockIdx.x * 256 + threadIdx.x; d < tot; d += gridDim.x * 256) {
    int chunk = d >> 13, r = d & 8191;
    int nt = r >> 9, lane = (r >> 3) & 63, j = r & 7;
    int q = lane >> 4, c = lane & 15;
    int k = chunk * 32 + q * 8 + j;
    dst[d] = (h16)src[(long)k * 256 + nt * 16 + c];
  }
}
__global__ void prepH_kernel(const float* __restrict__ src, h16* __restrict__ dst) {
  for (int d = blockIdx.x * 256 + threadIdx.x; d < 4096; d += gridDim.x * 256) {
    int kk = d >> 9, lane = (d >> 3) & 63, j = d & 7;
    int q = lane >> 4, c = lane & 15;
    int k = kk * 32 + q * 8 + j;
    dst[d] = (h16)((c < 10) ? src[k * 10 + c] : 0.0f);
  }
}

// ================= mega kernel: (optional in-proj) + 6 fused FFN+LN iterations =================
// 512 thr (8 waves), wave owns 32 rows = 2 A-tiles -> 2 MFMA per B-fragment read.
// sched_barrier fences cap the scheduler's ds_read lookahead (<=16 regs) so peak
// liveness stays under the 256-reg/wave cap -> no scratch spills (round-4 lesson).
__global__ __launch_bounds__(512, 2) void mega_kernel(
    const float* x, h16* zy,
    const char* __restrict__ winP, const char* __restrict__ wupP, const char* __restrict__ wdnP,
    const float* __restrict__ b_in, const float* __restrict__ b_up,
    const float* __restrict__ b_down, const float* __restrict__ ln_w,
    const float* __restrict__ ln_b, const float* __restrict__ y_init, int first) {
  extern __shared__ char smem[];
  const int tid = threadIdx.x, wave = tid >> 6, lane = tid & 63;
  const int q = lane >> 4, c = lane & 15;
  const int lane16 = lane << 4;
  const long m0 = (long)blockIdx.x * 256 + wave * 32;   // tile a: m0.., tile b: m0+16..

  float* bupL = (float*)(smem + L_BUP);
  float* bdnL = (float*)(smem + L_BDN);
  float* lnwL = (float*)(smem + L_LNW);
  float* lnbL = (float*)(smem + L_LNB);
  for (int i = tid; i < 1024; i += 512) bupL[i] = b_up[i];
  if (tid < 256) { bdnL[tid] = b_down[tid]; lnwL[tid] = ln_w[tid]; lnbL[tid] = ln_b[tid]; }

  f32x4 acc2a[16], acc2b[16];  // z accumulators, D-layout: row = q*4+r, col = nt*16+c
  h16x8 aza[8], azb[8];        // A-fragments: A[m=c][k=kk*32+q*8+j]
  h16* sl = (h16*)(smem + L_HS + wave * (32 * SLICE_W * 2));
  const f32x4 vzero = {0.0f, 0.0f, 0.0f, 0.0f};

  if (first) {
    // ---- in-proj: z = x @ W_in + b_in ----
#pragma unroll
    for (int kk = 0; kk < 8; ++kk) {
      const float* pa = x + (m0 + c) * 256 + kk * 32 + q * 8;
      f32x4 u0 = *(const f32x4*)pa;
      f32x4 u1 = *(const f32x4*)(pa + 4);
      h16x8 a;
      a[0] = (h16)u0[0]; a[1] = (h16)u0[1]; a[2] = (h16)u0[2]; a[3] = (h16)u0[3];
      a[4] = (h16)u1[0]; a[5] = (h16)u1[1]; a[6] = (h16)u1[2]; a[7] = (h16)u1[3];
      aza[kk] = a;
      const float* pb = x + (m0 + 16 + c) * 256 + kk * 32 + q * 8;
      u0 = *(const f32x4*)pb;
      u1 = *(const f32x4*)(pb + 4);
      a[0] = (h16)u0[0]; a[1] = (h16)u0[1]; a[2] = (h16)u0[2]; a[3] = (h16)u0[3];
      a[4] = (h16)u1[0]; a[5] = (h16)u1[1]; a[6] = (h16)u1[2]; a[7] = (h16)u1[3];
      azb[kk] = a;
      SFENCE;
    }
#pragma unroll
    for (int nt = 0; nt < 16; ++nt) { acc2a[nt] = vzero; acc2b[nt] = vzero; }

    stage_calls(winP, smem + L_WUP0, 16, wave, 8, lane);
    __syncthreads();
#pragma unroll
    for (int ncI = 0; ncI < 8; ++ncI) {
      if (ncI < 7)
        stage_calls(winP + (ncI + 1) * WIN_CSH, smem + (((ncI + 1) & 1) ? L_WUP1 : L_WUP0),
                    16, wave, 8, lane);
      const char* wb = smem + ((ncI & 1) ? L_WUP1 : L_WUP0);
#pragma unroll
      for (int kk = 0; kk < 8; ++kk) {
#pragma unroll
        for (int nt = 0; nt < 2; ++nt) {
          h16x8 b = *(const h16x8*)(wb + ((kk * 2 + nt) << 10) + lane16);
          acc2a[ncI * 2 + nt] = MFMA16(aza[kk], b, acc2a[ncI * 2 + nt]);
          acc2b[ncI * 2 + nt] = MFMA16(azb[kk], b, acc2b[ncI * 2 + nt]);
        }
        if ((kk & 1) == 1) SFENCE;
      }
      __syncthreads();
    }
#pragma unroll
    for (int nt = 0; nt < 16; ++nt) {
      float bi = b_in[nt * 16 + c];
#pragma unroll
      for (int r = 0; r < 4; ++r) { acc2a[nt][r] += bi; acc2b[nt][r] += bi; }
    }
    // ---- y-half = y_init (comb's concatenated GEMM reads it) ----
#pragma unroll
    for (int kk = 0; kk < 8; ++kk) {
      const float* p = y_init + kk * 32 + q * 8;
      f32x4 u0 = *(const f32x4*)p;
      f32x4 u1 = *(const f32x4*)(p + 4);
      h16x8 a;
      a[0] = (h16)u0[0]; a[1] = (h16)u0[1]; a[2] = (h16)u0[2]; a[3] = (h16)u0[3];
      a[4] = (h16)u1[0]; a[5] = (h16)u1[1]; a[6] = (h16)u1[2]; a[7] = (h16)u1[3];
      *(h16x8*)(zy + (m0 + c) * 512 + 256 + kk * 32 + q * 8) = a;
      *(h16x8*)(zy + (m0 + 16 + c) * 512 + 256 + kk * 32 + q * 8) = a;
    }
    stage_calls(wupP, smem + L_WUP0, 16, wave, 8, lane);
    stage_calls(wdnP, smem + L_WDN0, 16, wave, 8, lane);
    // d2a: az := A-fragments of z for iteration 0 (inlined, per tile)
#pragma unroll
    for (int kk = 0; kk < 8; ++kk) {
#pragma unroll
      for (int n2 = 0; n2 < 2; ++n2)
#pragma unroll
        for (int r = 0; r < 4; ++r)
          sl[(q * 4 + r) * SLICE_W + n2 * 16 + c] = (h16)acc2a[kk * 2 + n2][r];
      aza[kk] = *(const h16x8*)(sl + c * SLICE_W + q * 8);
    }
    SFENCE;
#pragma unroll
    for (int kk = 0; kk < 8; ++kk) {
#pragma unroll
      for (int n2 = 0; n2 < 2; ++n2)
#pragma unroll
        for (int r = 0; r < 4; ++r)
          sl[(16 + q * 4 + r) * SLICE_W + n2 * 16 + c] = (h16)acc2b[kk * 2 + n2][r];
      azb[kk] = *(const h16x8*)(sl + (16 + c) * SLICE_W + q * 8);
    }
  } else {
    stage_calls(wupP, smem + L_WUP0, 16, wave, 8, lane);
    stage_calls(wdnP, smem + L_WDN0, 16, wave, 8, lane);
    // resume z: A-form native in zy; D-form via slice (inlined a2d, per tile)
#pragma unroll
    for (int kk = 0; kk < 8; ++kk) {
      aza[kk] = *(const h16x8*)(zy + (m0 + c) * 512 + kk * 32 + q * 8);
      azb[kk] = *(const h16x8*)(zy + (m0 + 16 + c) * 512 + kk * 32 + q * 8);
    }
#pragma unroll
    for (int kk = 0; kk < 8; ++kk) {
      *(h16x8*)(sl + c * SLICE_W + q * 8) = aza[kk];
#pragma unroll
      for (int n2 = 0; n2 < 2; ++n2)
#pragma unroll
        for (int r = 0; r < 4; ++r)
          acc2a[kk * 2 + n2][r] = (float)sl[(q * 4 + r) * SLICE_W + n2 * 16 + c];
      SFENCE;
    }
#pragma unroll
    for (int kk = 0; kk < 8; ++kk) {
      *(h16x8*)(sl + (16 + c) * SLICE_W + q * 8) = azb[kk];
#pragma unroll
      for (int n2 = 0; n2 < 2; ++n2)
#pragma unroll
        for (int r = 0; r < 4; ++r)
          acc2b[kk * 2 + n2][r] = (float)sl[(16 + q * 4 + r) * SLICE_W + n2 * 16 + c];
      SFENCE;
    }
  }

  for (int it = 0; it < 6; ++it) {
    for (int nc = 0; nc < 32; ++nc) {
      const int tc = it * 32 + nc;
      __syncthreads();  // staged chunk tc landed (its loads were issued a full chunk ago)
      if (tc < 191) {
        const int nxt = (nc + 1) & 31;
        char* wu = smem + (((tc + 1) & 1) ? L_WUP1 : L_WUP0);
        char* wd = smem + (((tc + 1) & 1) ? L_WDN1 : L_WDN0);
        stage_calls(wupP + nxt * WUP_CSH, wu, 16, wave, 8, lane);
        stage_calls(wdnP + nxt * WDN_CSH, wd, 16, wave, 8, lane);
      }
      const char* wub = smem + ((tc & 1) ? L_WUP1 : L_WUP0);
      const char* wdb = smem + ((tc & 1) ? L_WDN1 : L_WDN0);

      // GEMM1: h_pre = z @ W_up[:, nc*32 : +32]  (one B read feeds both A-tiles)
      f32x4 acc1a0 = vzero, acc1a1 = vzero, acc1b0 = vzero, acc1b1 = vzero;
#pragma unroll
      for (int kk = 0; kk < 8; ++kk) {
        h16x8 b0 = *(const h16x8*)(wub + ((kk * 2 + 0) << 10) + lane16);
        acc1a0 = MFMA16(aza[kk], b0, acc1a0);
        acc1b0 = MFMA16(azb[kk], b0, acc1b0);
        h16x8 b1 = *(const h16x8*)(wub + ((kk * 2 + 1) << 10) + lane16);
        acc1a1 = MFMA16(aza[kk], b1, acc1a1);
        acc1b1 = MFMA16(azb[kk], b1, acc1b1);
        if ((kk & 1) == 1) SFENCE;   // cap ds_read lookahead -> no reg spike
      }
      // gelu + bias -> slice rows [0..31]
      {
        float bu0 = bupL[nc * 32 + c];
        float bu1 = bupL[nc * 32 + 16 + c];
#pragma unroll
        for (int r = 0; r < 4; ++r) {
          sl[(q * 4 + r) * SLICE_W + c] = (h16)gelu_f(acc1a0[r] + bu0);
          sl[(q * 4 + r) * SLICE_W + 16 + c] = (h16)gelu_f(acc1a1[r] + bu1);
          sl[(16 + q * 4 + r) * SLICE_W + c] = (h16)gelu_f(acc1b0[r] + bu0);
          sl[(16 + q * 4 + r) * SLICE_W + 16 + c] = (h16)gelu_f(acc1b1[r] + bu1);
        }
      }
      SFENCE;
      h16x8 ah0 = *(const h16x8*)(sl + c * SLICE_W + q * 8);
      h16x8 ah1 = *(const h16x8*)(sl + (16 + c) * SLICE_W + q * 8);
      // GEMM2: acc2 += h @ W_down[nc*32 : +32, :]  (one B read feeds both A-tiles)
#pragma unroll
      for (int nt = 0; nt < 16; ++nt) {
        h16x8 b = *(const h16x8*)(wdb + (nt << 10) + lane16);
        acc2a[nt] = MFMA16(ah0, b, acc2a[nt]);
        acc2b[nt] = MFMA16(ah1, b, acc2b[nt]);
        if ((nt & 3) == 3) SFENCE;   // cap ds_read lookahead -> no reg spike
      }
    }

    // ---- fused epilogue: + b_down, LayerNorm normalize-in-place (per tile, flat) ----
    {
      float sum[4] = {0, 0, 0, 0}, sq[4] = {0, 0, 0, 0};
#pragma unroll
      for (int nt = 0; nt < 16; ++nt) {
        float bd = bdnL[nt * 16 + c];
#pragma unroll
        for (int r = 0; r < 4; ++r) {
          float v = acc2a[nt][r] + bd;
          acc2a[nt][r] = v;
          sum[r] += v;
          sq[r] += v * v;
        }
      }
#pragma unroll
      for (int r = 0; r < 4; ++r)
#pragma unroll
        for (int m = 1; m < 16; m <<= 1) {
          sum[r] += __shfl_xor(sum[r], m, 16);
          sq[r] += __shfl_xor(sq[r], m, 16);
        }
#pragma unroll
      for (int r = 0; r < 4; ++r) {
        float mu = sum[r] * (1.0f / 256.0f);
        float var = sq[r] * (1.0f / 256.0f) - mu * mu;
        float rs = __builtin_amdgcn_rsqf(var + 1e-5f);
        sum[r] = mu; sq[r] = rs;
      }
#pragma unroll
      for (int nt = 0; nt < 16; ++nt) {
        float w = lnwL[nt * 16 + c], bb = lnbL[nt * 16 + c];
#pragma unroll
        for (int r = 0; r < 4; ++r)
          acc2a[nt][r] = (acc2a[nt][r] - sum[r]) * sq[r] * w + bb;
      }
    }
    SFENCE;
    {
      float sum[4] = {0, 0, 0, 0}, sq[4] = {0, 0, 0, 0};
#pragma unroll
      for (int nt = 0; nt < 16; ++nt) {
        float bd = bdnL[nt * 16 + c];
#pragma unroll
        for (int r = 0; r < 4; ++r) {
          float v = acc2b[nt][r] + bd;
          acc2b[nt][r] = v;
          sum[r] += v;
          sq[r] += v * v;
        }
      }
#pragma unroll
      for (int r = 0; r < 4; ++r)
#pragma unroll
        for (int m = 1; m < 16; m <<= 1) {
          sum[r] += __shfl_xor(sum[r], m, 16);
          sq[r] += __shfl_xor(sq[r], m, 16);
        }
#pragma unroll
      for (int r = 0; r < 4; ++r) {
        float mu = sum[r] * (1.0f / 256.0f);
        float var = sq[r] * (1.0f / 256.0f) - mu * mu;
        float rs = __builtin_amdgcn_rsqf(var + 1e-5f);
        sum[r] = mu; sq[r] = rs;
      }
#pragma unroll
      for (int nt = 0; nt < 16; ++nt) {
        float w = lnwL[nt * 16 + c], bb = lnbL[nt * 16 + c];
#pragma unroll
        for (int r = 0; r < 4; ++r)
          acc2b[nt][r] = (acc2b[nt][r] - sum[r]) * sq[r] * w + bb;
      }
    }
    SFENCE;
    if (it < 5) {
      // d2a for next iteration (per tile)
#pragma unroll
      for (int kk = 0; kk < 8; ++kk) {
#pragma unroll
        for (int n2 = 0; n2 < 2; ++n2)
#pragma unroll
          for (int r = 0; r < 4; ++r)
            sl[(q * 4 + r) * SLICE_W + n2 * 16 + c] = (h16)acc2a[kk * 2 + n2][r];
        aza[kk] = *(const h16x8*)(sl + c * SLICE_W + q * 8);
      }
      SFENCE;
#pragma unroll
      for (int kk = 0; kk < 8; ++kk) {
#pragma unroll
        for (int n2 = 0; n2 < 2; ++n2)
#pragma unroll
          for (int r = 0; r < 4; ++r)
            sl[(16 + q * 4 + r) * SLICE_W + n2 * 16 + c] = (h16)acc2b[kk * 2 + n2][r];
        azb[kk] = *(const h16x8*)(sl + (16 + c) * SLICE_W + q * 8);
      }
      SFENCE;
    }
  }

  // ---- hand off z (fp16, full-line stores via slice, inlined d2g per tile) ----
#pragma unroll
  for (int kk = 0; kk < 8; ++kk) {
#pragma unroll
    for (int n2 = 0; n2 < 2; ++n2)
#pragma unroll
      for (int r = 0; r < 4; ++r)
        sl[(q * 4 + r) * SLICE_W + n2 * 16 + c] = (h16)acc2a[kk * 2 + n2][r];
    *(h16x8*)(zy + (m0 + c) * 512 + kk * 32 + q * 8) =
        *(const h16x8*)(sl + c * SLICE_W + q * 8);
  }
  SFENCE;
#pragma unroll
  for (int kk = 0; kk < 8; ++kk) {
#pragma unroll
    for (int n2 = 0; n2 < 2; ++n2)
#pragma unroll
      for (int r = 0; r < 4; ++r)
        sl[(16 + q * 4 + r) * SLICE_W + n2 * 16 + c] = (h16)acc2b[kk * 2 + n2][r];
    *(h16x8*)(zy + (m0 + 16 + c) * 512 + kk * 32 + q * 8) =
        *(const h16x8*)(sl + (16 + c) * SLICE_W + q * 8);
  }
}

// ================= comb kernel: g = gelu([z|y]@W_comb + b_comb); y += g@W_yt + b_yt =================
__global__ __launch_bounds__(512, 2) void comb_kernel(
    h16* zy, const char* __restrict__ wcP, const char* __restrict__ wytP,
    const float* __restrict__ b_comb, const float* __restrict__ b_yt,
    const float* __restrict__ y_init, int first) {
  extern __shared__ char smem[];
  const int tid = threadIdx.x, wave = tid >> 6, lane = tid & 63;
  const int q = lane >> 4, c = lane & 15;
  const int lane16 = lane << 4;
  const long m0 = (long)blockIdx.x * 128 + wave * 16;

  float* bcL = (float*)(smem + C_BC);
  float* byL = (float*)(smem + C_BY);
  if (tid < 256) { bcL[tid] = b_comb[tid]; byL[tid] = b_yt[tid]; }

  h16* sl = (h16*)(smem + C_GS + wave * (SLICE_W * 16 * 2));
  const f32x4 vzero = {0.0f, 0.0f, 0.0f, 0.0f};

  stage_calls(wcP, smem + C_WC0, 32, wave, 8, lane);
  stage_calls(wytP, smem + C_WY0, 16, wave, 8, lane);

  // full [z|y] row cached in registers across all 8 chunks (64 VGPR)
  h16x8 a[16];
#pragma unroll
  for (int kk = 0; kk < 16; ++kk)
    a[kk] = *(const h16x8*)(zy + (m0 + c) * 512 + kk * 32 + q * 8);

  f32x4 acc2[16];  // y accumulator
  if (first) {
#pragma unroll
    for (int nt = 0; nt < 16; ++nt) {
      float yv = y_init[nt * 16 + c];
#pragma unroll
      for (int r = 0; r < 4; ++r) acc2[nt][r] = yv;
    }
  } else {
    // y D-form from the cached y fragments (a[8..15]) via slice (inlined a2d)
#pragma unroll
    for (int kk = 0; kk < 8; ++kk) {
      *(h16x8*)(sl + c * SLICE_W + q * 8) = a[8 + kk];
#pragma unroll
      for (int n2 = 0; n2 < 2; ++n2)
#pragma unroll
        for (int r = 0; r < 4; ++r)
          acc2[kk * 2 + n2][r] = (float)sl[(q * 4 + r) * SLICE_W + n2 * 16 + c];
      SFENCE;
    }
  }

  for (int nc = 0; nc < 8; ++nc) {
    __syncthreads();
    if (nc < 7) {
      int nb = (nc + 1) & 1;
      stage_calls(wcP + (nc + 1) * WCOMB_CSH, smem + (nb ? C_WC1 : C_WC0), 32, wave, 8, lane);
      stage_calls(wytP + (nc + 1) * WYT_CSH, smem + (nb ? C_WY1 : C_WY0), 16, wave, 8, lane);
    }
    const char* wcb = smem + ((nc & 1) ? C_WC1 : C_WC0);
    const char* wyb = smem + ((nc & 1) ? C_WY1 : C_WY0);

    // GEMM-g: [z|y] @ W_comb[:, nc*32 : +32]
    f32x4 acc1[2];
    acc1[0] = vzero; acc1[1] = vzero;
#pragma unroll
    for (int kk = 0; kk < 16; ++kk) {
#pragma unroll
      for (int nt = 0; nt < 2; ++nt) {
        h16x8 b = *(const h16x8*)(wcb + ((kk * 2 + nt) << 10) + lane16);
        acc1[nt] = MFMA16(a[kk], b, acc1[nt]);
      }
      if ((kk & 3) == 3) SFENCE;
    }
#pragma unroll
    for (int nt = 0; nt < 2; ++nt) {
      float bc = bcL[nc * 32 + nt * 16 + c];
#pragma unroll
      for (int r = 0; r < 4; ++r) {
        float g = gelu_f(acc1[nt][r] + bc);
        sl[(q * 4 + r) * SLICE_W + nt * 16 + c] = (h16)g;
      }
    }
    SFENCE;
    h16x8 ah = *(const h16x8*)(sl + c * SLICE_W + q * 8);
#pragma unroll
    for (int nt = 0; nt < 16; ++nt) {
      h16x8 b = *(const h16x8*)(wyb + (nt << 10) + lane16);
      acc2[nt] = MFMA16(ah, b, acc2[nt]);
      if ((nt & 3) == 3) SFENCE;
    }
  }

  // ---- y store: + b_yt, slice, full-line stores (inlined d2g) ----
#pragma unroll
  for (int kk = 0; kk < 8; ++kk) {
#pragma unroll
    for (int n2 = 0; n2 < 2; ++n2) {
      float by = byL[(kk * 2 + n2) * 16 + c];
#pragma unroll
      for (int r = 0; r < 4; ++r)
        sl[(q * 4 + r) * SLICE_W + n2 * 16 + c] = (h16)(acc2[kk * 2 + n2][r] + by);
    }
    *(h16x8*)(zy + (m0 + c) * 512 + 256 + kk * 32 + q * 8) =
        *(const h16x8*)(sl + c * SLICE_W + q * 8);
  }
}

// ================= head kernel: out = y @ W_head + b_head =================
__global__ __launch_bounds__(256) void head_kernel(const h16* zy, const char* __restrict__ whP,
                                                   const float* __restrict__ b_head,
                                                   float* __restrict__ out) {
  extern __shared__ char smem[];
  const int tid = threadIdx.x, wave = tid >> 6, lane = tid & 63;
  const int q = lane >> 4, c = lane & 15;
  const int lane16 = lane << 4;
  const long m0 = (long)blockIdx.x * 128 + wave * 32;

  stage_calls(whP, smem, 8, wave, 4, lane);
  __syncthreads();

  f32x4 acc[2];
  const f32x4 vzero = {0.0f, 0.0f, 0.0f, 0.0f};
  acc[0] = vzero; acc[1] = vzero;
#pragma unroll
  for (int kk = 0; kk < 8; ++kk) {
    h16x8 b = *(const h16x8*)(smem + (kk << 10) + lane16);
#pragma unroll
    for (int rt = 0; rt < 2; ++rt) {
      h16x8 a = *(const h16x8*)(zy + (m0 + rt * 16 + c) * 512 + 256 + kk * 32 + q * 8);
      acc[rt] = MFMA16(a, b, acc[rt]);
    }
  }
  if (c < 10) {
    float bh = b_head[c];
#pragma unroll
    for (int rt = 0; rt < 2; ++rt)
#pragma unroll
      for (int r = 0; r < 4; ++r)
        out[(m0 + rt * 16 + q * 4 + r) * 10 + c] = acc[rt][r] + bh;
  }
}

// ================= host =================
extern "C" void kernel_launch(void* const* d_in, const int* in_sizes, int n_in, void* d_out,
                              int out_size, void* d_ws, size_t ws_size, hipStream_t stream) {
  (void)in_sizes; (void)n_in; (void)out_size;
  const float* x      = (const float*)d_in[0];
  const float* W_in   = (const float*)d_in[1];
  const float* b_in   = (const float*)d_in[2];
  const float* y_init = (const float*)d_in[3];
  const float* W_up   = (const float*)d_in[4];
  const float* b_up   = (const float*)d_in[5];
  const float* W_down = (const float*)d_in[6];
  const float* b_down = (const float*)d_in[7];
  const float* ln_w   = (const float*)d_in[8];
  const float* ln_b   = (const float*)d_in[9];
  const float* W_comb = (const float*)d_in[10];
  const float* b_comb = (const float*)d_in[11];
  const float* W_yt   = (const float*)d_in[12];
  const float* b_yt   = (const float*)d_in[13];
  const float* W_head = (const float*)d_in[14];
  const float* b_head = (const float*)d_in[15];

  char* ws = (char*)d_ws;
  h16* winP   = (h16*)(ws + WIN_OFF);
  h16* wupP   = (h16*)(ws + WUP_OFF);
  h16* wdnP   = (h16*)(ws + WDN_OFF);
  h16* wcombP = (h16*)(ws + WCOMB_OFF);
  h16* wytP   = (h16*)(ws + WYT_OFF);
  h16* wheadP = (h16*)(ws + WHEAD_OFF);
  h16* zy = (ws_size >= (size_t)ZY_OFF + ZY_BYTES) ? (h16*)(ws + ZY_OFF) : (h16*)d_in[0];

  hipFuncSetAttribute((const void*)mega_kernel, hipFuncAttributeMaxDynamicSharedMemorySize,
                      SMEM_MEGA);
  hipFuncSetAttribute((const void*)comb_kernel, hipFuncAttributeMaxDynamicSharedMemorySize,
                      SMEM_COMB);

  // prep: cast + fragment-major blocking of all weights
  {
    int tot;
    tot = 8 * (WIN_CSH / 2);
    prepC_kernel<<<dim3((tot + 255) / 256), dim3(256), 0, stream>>>(W_in, winP, 256, WIN_CSH / 2, tot);
    tot = 32 * (WUP_CSH / 2);
    prepC_kernel<<<dim3((tot + 255) / 256), dim3(256), 0, stream>>>(W_up, wupP, 1024, WUP_CSH / 2, tot);
    tot = 8 * (WCOMB_CSH / 2);
    prepC_kernel<<<dim3((tot + 255) / 256), dim3(256), 0, stream>>>(W_comb, wcombP, 256, WCOMB_CSH / 2, tot);
    tot = 32 * (WDN_CSH / 2);
    prepD_kernel<<<dim3((tot + 255) / 256), dim3(256), 0, stream>>>(W_down, wdnP, tot);
    tot = 8 * (WYT_CSH / 2);
    prepD_kernel<<<dim3((tot + 255) / 256), dim3(256), 0, stream>>>(W_yt, wytP, tot);
    prepH_kernel<<<dim3(16), dim3(256), 0, stream>>>(W_head, wheadP);
  }

  for (int h = 0; h < 3; ++h) {
    mega_kernel<<<dim3(512), dim3(512), SMEM_MEGA, stream>>>(
        x, zy, (const char*)winP, (const char*)wupP, (const char*)wdnP, b_in, b_up, b_down,
        ln_w, ln_b, y_init, (h == 0) ? 1 : 0);
    comb_kernel<<<dim3(1024), dim3(512), SMEM_COMB, stream>>>(
        zy, (const char*)wcombP, (const char*)wytP, b_comb, b_yt, y_init, (h == 0) ? 1 : 0);
  }
  head_kernel<<<dim3(1024), dim3(256), SMEM_HEAD, stream>>>(zy, (const char*)wheadP, b_head,
                                                            (float*)d_out);
}

// Round 6
// 4082.114 us; speedup vs baseline: 1.0883x; 1.0883x over previous
//
#include <hip/hip_runtime.h>

typedef _Float16 h16;
typedef h16 h16x8 __attribute__((ext_vector_type(8)));
typedef float f32x4 __attribute__((ext_vector_type(4)));

#define MFMA16(a, b, c) __builtin_amdgcn_mfma_f32_16x16x32_f16(a, b, c, 0, 0, 0)

typedef __attribute__((address_space(1))) const char gconst_char;
typedef __attribute__((address_space(3))) char lds_char;
#define GL_LDS16(g, l) __builtin_amdgcn_global_load_lds((gconst_char*)(g), (lds_char*)(l), 16, 0, 0)

// ---------------- workspace layout (bytes) ----------------
// Fragment-major fp16 weight blocks: B-fragment f of a chunk at chunk_base + f*1024 + lane*16.
#define WIN_CSH   16384                    // [frag 16][lane 64][16B], 8 chunks
#define WIN_OFF   0
#define WUP_CSH   16384                    // 32 chunks
#define WUP_OFF   131072
#define WDN_CSH   16384                    // 32 chunks
#define WDN_OFF   655360
#define WCOMB_CSH 32768                    // [frag 32][lane 64][16B], 8 chunks
#define WCOMB_OFF 1179648
#define WYT_CSH   16384                    // 8 chunks
#define WYT_OFF   1441792
#define WHEAD_SZ  8192                     // [frag 8][lane 64][16B]
#define WHEAD_OFF 1572864
#define ZY_OFF    1581056
#define ZY_BYTES  (131072UL * 512UL * 2UL) // [B][512] halfs: z cols 0..255, y cols 256..511

// ---------------- mega kernel LDS (8 waves x 32 rows) ----------------
#define L_WUP0 0
#define L_WUP1 16384
#define L_WDN0 32768
#define L_WDN1 49152
#define L_HS   65536        // + wave*2688 : [32][42] halfs per wave (chunk Hs + transposes)
#define L_BUP  87040        // f32[1024]
#define L_BDN  91136        // f32[256]
#define L_LNW  92160
#define L_LNB  93184
#define SMEM_MEGA 94208     // 1 block/CU

// ---------------- comb kernel LDS (8 waves x 16 rows) ----------------
#define C_WC0 0
#define C_WC1 32768
#define C_WY0 65536
#define C_WY1 81920
#define C_GS  98304         // + wave*1344
#define C_BC  109056        // f32[256]
#define C_BY  110080
#define SMEM_COMB 111104

#define SMEM_HEAD 8192

#define SLICE_W 42          // halfs; stride 21 dwords coprime with 32 banks -> conflict-free

__device__ __forceinline__ void stage_calls(const char* src, char* dst, int calls, int wave,
                                            int nw, int lane) {
  for (int i = wave; i < calls; i += nw)
    GL_LDS16(src + i * 1024 + lane * 16, dst + i * 1024);
}

__device__ __forceinline__ float gelu_f(float x) {
  float t = x * (1.5957691216f + 0.0713548354f * x * x);
  float e = __expf(-t);
  return x * __builtin_amdgcn_rcpf(1.0f + e);
}

// ================= prep kernels: fp32 -> fp16 fragment-major blocks =================
__global__ void prepC_kernel(const float* __restrict__ src, h16* __restrict__ dst,
                             int Nsrc, int CSHh, int tot) {
  for (int d = blockIdx.x * 256 + threadIdx.x; d < tot; d += gridDim.x * 256) {
    int chunk = d / CSHh, r = d % CSHh;
    int frag = r >> 9, lane = (r >> 3) & 63, j = r & 7;
    int kk = frag >> 1, nt = frag & 1, q = lane >> 4, c = lane & 15;
    int k = kk * 32 + q * 8 + j;
    int n = chunk * 32 + nt * 16 + c;
    dst[d] = (h16)src[(long)k * Nsrc + n];
  }
}
__global__ void prepD_kernel(const float* __restrict__ src, h16* __restrict__ dst, int tot) {
  for (int d = blockIdx.x * 256 + threadIdx.x; d < tot; d += gridDim.x * 256) {
    int chunk = d >> 13, r = d & 8191;
    int nt = r >> 9, lane = (r >> 3) & 63, j = r & 7;
    int q = lane >> 4, c = lane & 15;
    int k = chunk * 32 + q * 8 + j;
    dst[d] = (h16)src[(long)k * 256 + nt * 16 + c];
  }
}
__global__ void prepH_kernel(const float* __restrict__ src, h16* __restrict__ dst) {
  for (int d = blockIdx.x * 256 + threadIdx.x; d < 4096; d += gridDim.x * 256) {
    int kk = d >> 9, lane = (d >> 3) & 63, j = d & 7;
    int q = lane >> 4, c = lane & 15;
    int k = kk * 32 + q * 8 + j;
    dst[d] = (h16)((c < 10) ? src[k * 10 + c] : 0.0f);
  }
}

// ================= mega kernel: (optional in-proj) + 6 fused FFN+LN iterations =================
// 512 thr (8 waves), wave owns 32 rows = 2 A-tiles -> 2 MFMA per B-fragment read.
// __launch_bounds__(512, 1): 1 block/CU (LDS-bound anyway) -> 256-reg/wave budget.
// The (512,2) variants were silently capped at 128 VGPRs -> per-chunk scratch spills.
__global__ __launch_bounds__(512, 1) void mega_kernel(
    const float* x, h16* zy,
    const char* __restrict__ winP, const char* __restrict__ wupP, const char* __restrict__ wdnP,
    const float* __restrict__ b_in, const float* __restrict__ b_up,
    const float* __restrict__ b_down, const float* __restrict__ ln_w,
    const float* __restrict__ ln_b, const float* __restrict__ y_init, int first) {
  extern __shared__ char smem[];
  const int tid = threadIdx.x, wave = tid >> 6, lane = tid & 63;
  const int q = lane >> 4, c = lane & 15;
  const int lane16 = lane << 4;
  const long m0 = (long)blockIdx.x * 256 + wave * 32;   // tile a: m0.., tile b: m0+16..

  float* bupL = (float*)(smem + L_BUP);
  float* bdnL = (float*)(smem + L_BDN);
  float* lnwL = (float*)(smem + L_LNW);
  float* lnbL = (float*)(smem + L_LNB);
  for (int i = tid; i < 1024; i += 512) bupL[i] = b_up[i];
  if (tid < 256) { bdnL[tid] = b_down[tid]; lnwL[tid] = ln_w[tid]; lnbL[tid] = ln_b[tid]; }

  f32x4 acc2a[16], acc2b[16];  // z accumulators, D-layout: row = q*4+r, col = nt*16+c
  h16x8 aza[8], azb[8];        // A-fragments: A[m=c][k=kk*32+q*8+j]
  h16* sl = (h16*)(smem + L_HS + wave * (32 * SLICE_W * 2));
  const f32x4 vzero = {0.0f, 0.0f, 0.0f, 0.0f};

  if (first) {
    // ---- in-proj: z = x @ W_in + b_in ----
#pragma unroll
    for (int kk = 0; kk < 8; ++kk) {
      const float* pa = x + (m0 + c) * 256 + kk * 32 + q * 8;
      f32x4 u0 = *(const f32x4*)pa;
      f32x4 u1 = *(const f32x4*)(pa + 4);
      h16x8 a;
      a[0] = (h16)u0[0]; a[1] = (h16)u0[1]; a[2] = (h16)u0[2]; a[3] = (h16)u0[3];
      a[4] = (h16)u1[0]; a[5] = (h16)u1[1]; a[6] = (h16)u1[2]; a[7] = (h16)u1[3];
      aza[kk] = a;
      const float* pb = x + (m0 + 16 + c) * 256 + kk * 32 + q * 8;
      u0 = *(const f32x4*)pb;
      u1 = *(const f32x4*)(pb + 4);
      a[0] = (h16)u0[0]; a[1] = (h16)u0[1]; a[2] = (h16)u0[2]; a[3] = (h16)u0[3];
      a[4] = (h16)u1[0]; a[5] = (h16)u1[1]; a[6] = (h16)u1[2]; a[7] = (h16)u1[3];
      azb[kk] = a;
    }
#pragma unroll
    for (int nt = 0; nt < 16; ++nt) { acc2a[nt] = vzero; acc2b[nt] = vzero; }

    stage_calls(winP, smem + L_WUP0, 16, wave, 8, lane);
    __syncthreads();
#pragma unroll
    for (int ncI = 0; ncI < 8; ++ncI) {
      if (ncI < 7)
        stage_calls(winP + (ncI + 1) * WIN_CSH, smem + (((ncI + 1) & 1) ? L_WUP1 : L_WUP0),
                    16, wave, 8, lane);
      const char* wb = smem + ((ncI & 1) ? L_WUP1 : L_WUP0);
#pragma unroll
      for (int kk = 0; kk < 8; ++kk) {
#pragma unroll
        for (int nt = 0; nt < 2; ++nt) {
          h16x8 b = *(const h16x8*)(wb + ((kk * 2 + nt) << 10) + lane16);
          acc2a[ncI * 2 + nt] = MFMA16(aza[kk], b, acc2a[ncI * 2 + nt]);
          acc2b[ncI * 2 + nt] = MFMA16(azb[kk], b, acc2b[ncI * 2 + nt]);
        }
      }
      __syncthreads();
    }
#pragma unroll
    for (int nt = 0; nt < 16; ++nt) {
      float bi = b_in[nt * 16 + c];
#pragma unroll
      for (int r = 0; r < 4; ++r) { acc2a[nt][r] += bi; acc2b[nt][r] += bi; }
    }
    // ---- y-half = y_init (comb's concatenated GEMM reads it) ----
#pragma unroll
    for (int kk = 0; kk < 8; ++kk) {
      const float* p = y_init + kk * 32 + q * 8;
      f32x4 u0 = *(const f32x4*)p;
      f32x4 u1 = *(const f32x4*)(p + 4);
      h16x8 a;
      a[0] = (h16)u0[0]; a[1] = (h16)u0[1]; a[2] = (h16)u0[2]; a[3] = (h16)u0[3];
      a[4] = (h16)u1[0]; a[5] = (h16)u1[1]; a[6] = (h16)u1[2]; a[7] = (h16)u1[3];
      *(h16x8*)(zy + (m0 + c) * 512 + 256 + kk * 32 + q * 8) = a;
      *(h16x8*)(zy + (m0 + 16 + c) * 512 + 256 + kk * 32 + q * 8) = a;
    }
    stage_calls(wupP, smem + L_WUP0, 16, wave, 8, lane);
    stage_calls(wdnP, smem + L_WDN0, 16, wave, 8, lane);
    // d2a: az := A-fragments of z for iteration 0 (inlined, per tile)
#pragma unroll
    for (int kk = 0; kk < 8; ++kk) {
#pragma unroll
      for (int n2 = 0; n2 < 2; ++n2)
#pragma unroll
        for (int r = 0; r < 4; ++r)
          sl[(q * 4 + r) * SLICE_W + n2 * 16 + c] = (h16)acc2a[kk * 2 + n2][r];
      aza[kk] = *(const h16x8*)(sl + c * SLICE_W + q * 8);
    }
#pragma unroll
    for (int kk = 0; kk < 8; ++kk) {
#pragma unroll
      for (int n2 = 0; n2 < 2; ++n2)
#pragma unroll
        for (int r = 0; r < 4; ++r)
          sl[(16 + q * 4 + r) * SLICE_W + n2 * 16 + c] = (h16)acc2b[kk * 2 + n2][r];
      azb[kk] = *(const h16x8*)(sl + (16 + c) * SLICE_W + q * 8);
    }
  } else {
    stage_calls(wupP, smem + L_WUP0, 16, wave, 8, lane);
    stage_calls(wdnP, smem + L_WDN0, 16, wave, 8, lane);
    // resume z: A-form native in zy; D-form via slice (inlined a2d, per tile)
#pragma unroll
    for (int kk = 0; kk < 8; ++kk) {
      aza[kk] = *(const h16x8*)(zy + (m0 + c) * 512 + kk * 32 + q * 8);
      azb[kk] = *(const h16x8*)(zy + (m0 + 16 + c) * 512 + kk * 32 + q * 8);
    }
#pragma unroll
    for (int kk = 0; kk < 8; ++kk) {
      *(h16x8*)(sl + c * SLICE_W + q * 8) = aza[kk];
#pragma unroll
      for (int n2 = 0; n2 < 2; ++n2)
#pragma unroll
        for (int r = 0; r < 4; ++r)
          acc2a[kk * 2 + n2][r] = (float)sl[(q * 4 + r) * SLICE_W + n2 * 16 + c];
    }
#pragma unroll
    for (int kk = 0; kk < 8; ++kk) {
      *(h16x8*)(sl + (16 + c) * SLICE_W + q * 8) = azb[kk];
#pragma unroll
      for (int n2 = 0; n2 < 2; ++n2)
#pragma unroll
        for (int r = 0; r < 4; ++r)
          acc2b[kk * 2 + n2][r] = (float)sl[(16 + q * 4 + r) * SLICE_W + n2 * 16 + c];
    }
  }

  for (int it = 0; it < 6; ++it) {
    for (int nc = 0; nc < 32; ++nc) {
      const int tc = it * 32 + nc;
      __syncthreads();  // staged chunk tc landed (its loads were issued a full chunk ago)
      if (tc < 191) {
        const int nxt = (nc + 1) & 31;
        char* wu = smem + (((tc + 1) & 1) ? L_WUP1 : L_WUP0);
        char* wd = smem + (((tc + 1) & 1) ? L_WDN1 : L_WDN0);
        stage_calls(wupP + nxt * WUP_CSH, wu, 16, wave, 8, lane);
        stage_calls(wdnP + nxt * WDN_CSH, wd, 16, wave, 8, lane);
      }
      const char* wub = smem + ((tc & 1) ? L_WUP1 : L_WUP0);
      const char* wdb = smem + ((tc & 1) ? L_WDN1 : L_WDN0);

      // GEMM1: h_pre = z @ W_up[:, nc*32 : +32], nt-major so only 2 acc1 tiles live
#pragma unroll
      for (int nt = 0; nt < 2; ++nt) {
        f32x4 aca = vzero, acb = vzero;
#pragma unroll
        for (int kk = 0; kk < 8; ++kk) {
          h16x8 b = *(const h16x8*)(wub + ((kk * 2 + nt) << 10) + lane16);
          aca = MFMA16(aza[kk], b, aca);
          acb = MFMA16(azb[kk], b, acb);
        }
        float bu = bupL[nc * 32 + nt * 16 + c];
#pragma unroll
        for (int r = 0; r < 4; ++r) {
          sl[(q * 4 + r) * SLICE_W + nt * 16 + c] = (h16)gelu_f(aca[r] + bu);
          sl[(16 + q * 4 + r) * SLICE_W + nt * 16 + c] = (h16)gelu_f(acb[r] + bu);
        }
      }
      h16x8 ah0 = *(const h16x8*)(sl + c * SLICE_W + q * 8);
      h16x8 ah1 = *(const h16x8*)(sl + (16 + c) * SLICE_W + q * 8);
      // GEMM2: acc2 += h @ W_down[nc*32 : +32, :]  (one B read feeds both A-tiles)
#pragma unroll
      for (int nt = 0; nt < 16; ++nt) {
        h16x8 b = *(const h16x8*)(wdb + (nt << 10) + lane16);
        acc2a[nt] = MFMA16(ah0, b, acc2a[nt]);
        acc2b[nt] = MFMA16(ah1, b, acc2b[nt]);
      }
    }

    // ---- fused epilogue: + b_down, LayerNorm normalize-in-place (per tile, flat) ----
    {
      float sum[4] = {0, 0, 0, 0}, sq[4] = {0, 0, 0, 0};
#pragma unroll
      for (int nt = 0; nt < 16; ++nt) {
        float bd = bdnL[nt * 16 + c];
#pragma unroll
        for (int r = 0; r < 4; ++r) {
          float v = acc2a[nt][r] + bd;
          acc2a[nt][r] = v;
          sum[r] += v;
          sq[r] += v * v;
        }
      }
#pragma unroll
      for (int r = 0; r < 4; ++r)
#pragma unroll
        for (int m = 1; m < 16; m <<= 1) {
          sum[r] += __shfl_xor(sum[r], m, 16);
          sq[r] += __shfl_xor(sq[r], m, 16);
        }
#pragma unroll
      for (int r = 0; r < 4; ++r) {
        float mu = sum[r] * (1.0f / 256.0f);
        float var = sq[r] * (1.0f / 256.0f) - mu * mu;
        float rs = __builtin_amdgcn_rsqf(var + 1e-5f);
        sum[r] = mu; sq[r] = rs;
      }
#pragma unroll
      for (int nt = 0; nt < 16; ++nt) {
        float w = lnwL[nt * 16 + c], bb = lnbL[nt * 16 + c];
#pragma unroll
        for (int r = 0; r < 4; ++r)
          acc2a[nt][r] = (acc2a[nt][r] - sum[r]) * sq[r] * w + bb;
      }
    }
    {
      float sum[4] = {0, 0, 0, 0}, sq[4] = {0, 0, 0, 0};
#pragma unroll
      for (int nt = 0; nt < 16; ++nt) {
        float bd = bdnL[nt * 16 + c];
#pragma unroll
        for (int r = 0; r < 4; ++r) {
          float v = acc2b[nt][r] + bd;
          acc2b[nt][r] = v;
          sum[r] += v;
          sq[r] += v * v;
        }
      }
#pragma unroll
      for (int r = 0; r < 4; ++r)
#pragma unroll
        for (int m = 1; m < 16; m <<= 1) {
          sum[r] += __shfl_xor(sum[r], m, 16);
          sq[r] += __shfl_xor(sq[r], m, 16);
        }
#pragma unroll
      for (int r = 0; r < 4; ++r) {
        float mu = sum[r] * (1.0f / 256.0f);
        float var = sq[r] * (1.0f / 256.0f) - mu * mu;
        float rs = __builtin_amdgcn_rsqf(var + 1e-5f);
        sum[r] = mu; sq[r] = rs;
      }
#pragma unroll
      for (int nt = 0; nt < 16; ++nt) {
        float w = lnwL[nt * 16 + c], bb = lnbL[nt * 16 + c];
#pragma unroll
        for (int r = 0; r < 4; ++r)
          acc2b[nt][r] = (acc2b[nt][r] - sum[r]) * sq[r] * w + bb;
      }
    }
    if (it < 5) {
      // d2a for next iteration (per tile)
#pragma unroll
      for (int kk = 0; kk < 8; ++kk) {
#pragma unroll
        for (int n2 = 0; n2 < 2; ++n2)
#pragma unroll
          for (int r = 0; r < 4; ++r)
            sl[(q * 4 + r) * SLICE_W + n2 * 16 + c] = (h16)acc2a[kk * 2 + n2][r];
        aza[kk] = *(const h16x8*)(sl + c * SLICE_W + q * 8);
      }
#pragma unroll
      for (int kk = 0; kk < 8; ++kk) {
#pragma unroll
        for (int n2 = 0; n2 < 2; ++n2)
#pragma unroll
          for (int r = 0; r < 4; ++r)
            sl[(16 + q * 4 + r) * SLICE_W + n2 * 16 + c] = (h16)acc2b[kk * 2 + n2][r];
        azb[kk] = *(const h16x8*)(sl + (16 + c) * SLICE_W + q * 8);
      }
    }
  }

  // ---- hand off z (fp16, full-line stores via slice, inlined d2g per tile) ----
#pragma unroll
  for (int kk = 0; kk < 8; ++kk) {
#pragma unroll
    for (int n2 = 0; n2 < 2; ++n2)
#pragma unroll
      for (int r = 0; r < 4; ++r)
        sl[(q * 4 + r) * SLICE_W + n2 * 16 + c] = (h16)acc2a[kk * 2 + n2][r];
    *(h16x8*)(zy + (m0 + c) * 512 + kk * 32 + q * 8) =
        *(const h16x8*)(sl + c * SLICE_W + q * 8);
  }
#pragma unroll
  for (int kk = 0; kk < 8; ++kk) {
#pragma unroll
    for (int n2 = 0; n2 < 2; ++n2)
#pragma unroll
      for (int r = 0; r < 4; ++r)
        sl[(16 + q * 4 + r) * SLICE_W + n2 * 16 + c] = (h16)acc2b[kk * 2 + n2][r];
    *(h16x8*)(zy + (m0 + 16 + c) * 512 + kk * 32 + q * 8) =
        *(const h16x8*)(sl + (16 + c) * SLICE_W + q * 8);
  }
}

// ================= comb kernel: g = gelu([z|y]@W_comb + b_comb); y += g@W_yt + b_yt =================
__global__ __launch_bounds__(512, 1) void comb_kernel(
    h16* zy, const char* __restrict__ wcP, const char* __restrict__ wytP,
    const float* __restrict__ b_comb, const float* __restrict__ b_yt,
    const float* __restrict__ y_init, int first) {
  extern __shared__ char smem[];
  const int tid = threadIdx.x, wave = tid >> 6, lane = tid & 63;
  const int q = lane >> 4, c = lane & 15;
  const int lane16 = lane << 4;
  const long m0 = (long)blockIdx.x * 128 + wave * 16;

  float* bcL = (float*)(smem + C_BC);
  float* byL = (float*)(smem + C_BY);
  if (tid < 256) { bcL[tid] = b_comb[tid]; byL[tid] = b_yt[tid]; }

  h16* sl = (h16*)(smem + C_GS + wave * (SLICE_W * 16 * 2));
  const f32x4 vzero = {0.0f, 0.0f, 0.0f, 0.0f};

  stage_calls(wcP, smem + C_WC0, 32, wave, 8, lane);
  stage_calls(wytP, smem + C_WY0, 16, wave, 8, lane);

  // full [z|y] row cached in registers across all 8 chunks (64 VGPR)
  h16x8 a[16];
#pragma unroll
  for (int kk = 0; kk < 16; ++kk)
    a[kk] = *(const h16x8*)(zy + (m0 + c) * 512 + kk * 32 + q * 8);

  f32x4 acc2[16];  // y accumulator
  if (first) {
#pragma unroll
    for (int nt = 0; nt < 16; ++nt) {
      float yv = y_init[nt * 16 + c];
#pragma unroll
      for (int r = 0; r < 4; ++r) acc2[nt][r] = yv;
    }
  } else {
    // y D-form from the cached y fragments (a[8..15]) via slice (inlined a2d)
#pragma unroll
    for (int kk = 0; kk < 8; ++kk) {
      *(h16x8*)(sl + c * SLICE_W + q * 8) = a[8 + kk];
#pragma unroll
      for (int n2 = 0; n2 < 2; ++n2)
#pragma unroll
        for (int r = 0; r < 4; ++r)
          acc2[kk * 2 + n2][r] = (float)sl[(q * 4 + r) * SLICE_W + n2 * 16 + c];
    }
  }

  for (int nc = 0; nc < 8; ++nc) {
    __syncthreads();
    if (nc < 7) {
      int nb = (nc + 1) & 1;
      stage_calls(wcP + (nc + 1) * WCOMB_CSH, smem + (nb ? C_WC1 : C_WC0), 32, wave, 8, lane);
      stage_calls(wytP + (nc + 1) * WYT_CSH, smem + (nb ? C_WY1 : C_WY0), 16, wave, 8, lane);
    }
    const char* wcb = smem + ((nc & 1) ? C_WC1 : C_WC0);
    const char* wyb = smem + ((nc & 1) ? C_WY1 : C_WY0);

    // GEMM-g: [z|y] @ W_comb[:, nc*32 : +32], nt-major (acc1 liveness 8 regs)
#pragma unroll
    for (int nt = 0; nt < 2; ++nt) {
      f32x4 ac = vzero;
#pragma unroll
      for (int kk = 0; kk < 16; ++kk) {
        h16x8 b = *(const h16x8*)(wcb + ((kk * 2 + nt) << 10) + lane16);
        ac = MFMA16(a[kk], b, ac);
      }
      float bc = bcL[nc * 32 + nt * 16 + c];
#pragma unroll
      for (int r = 0; r < 4; ++r)
        sl[(q * 4 + r) * SLICE_W + nt * 16 + c] = (h16)gelu_f(ac[r] + bc);
    }
    h16x8 ah = *(const h16x8*)(sl + c * SLICE_W + q * 8);
#pragma unroll
    for (int nt = 0; nt < 16; ++nt) {
      h16x8 b = *(const h16x8*)(wyb + (nt << 10) + lane16);
      acc2[nt] = MFMA16(ah, b, acc2[nt]);
    }
  }

  // ---- y store: + b_yt, slice, full-line stores (inlined d2g) ----
#pragma unroll
  for (int kk = 0; kk < 8; ++kk) {
#pragma unroll
    for (int n2 = 0; n2 < 2; ++n2) {
      float by = byL[(kk * 2 + n2) * 16 + c];
#pragma unroll
      for (int r = 0; r < 4; ++r)
        sl[(q * 4 + r) * SLICE_W + n2 * 16 + c] = (h16)(acc2[kk * 2 + n2][r] + by);
    }
    *(h16x8*)(zy + (m0 + c) * 512 + 256 + kk * 32 + q * 8) =
        *(const h16x8*)(sl + c * SLICE_W + q * 8);
  }
}

// ================= head kernel: out = y @ W_head + b_head =================
__global__ __launch_bounds__(256) void head_kernel(const h16* zy, const char* __restrict__ whP,
                                                   const float* __restrict__ b_head,
                                                   float* __restrict__ out) {
  extern __shared__ char smem[];
  const int tid = threadIdx.x, wave = tid >> 6, lane = tid & 63;
  const int q = lane >> 4, c = lane & 15;
  const int lane16 = lane << 4;
  const long m0 = (long)blockIdx.x * 128 + wave * 32;

  stage_calls(whP, smem, 8, wave, 4, lane);
  __syncthreads();

  f32x4 acc[2];
  const f32x4 vzero = {0.0f, 0.0f, 0.0f, 0.0f};
  acc[0] = vzero; acc[1] = vzero;
#pragma unroll
  for (int kk = 0; kk < 8; ++kk) {
    h16x8 b = *(const h16x8*)(smem + (kk << 10) + lane16);
#pragma unroll
    for (int rt = 0; rt < 2; ++rt) {
      h16x8 a = *(const h16x8*)(zy + (m0 + rt * 16 + c) * 512 + 256 + kk * 32 + q * 8);
      acc[rt] = MFMA16(a, b, acc[rt]);
    }
  }
  if (c < 10) {
    float bh = b_head[c];
#pragma unroll
    for (int rt = 0; rt < 2; ++rt)
#pragma unroll
      for (int r = 0; r < 4; ++r)
        out[(m0 + rt * 16 + q * 4 + r) * 10 + c] = acc[rt][r] + bh;
  }
}

// ================= host =================
extern "C" void kernel_launch(void* const* d_in, const int* in_sizes, int n_in, void* d_out,
                              int out_size, void* d_ws, size_t ws_size, hipStream_t stream) {
  (void)in_sizes; (void)n_in; (void)out_size;
  const float* x      = (const float*)d_in[0];
  const float* W_in   = (const float*)d_in[1];
  const float* b_in   = (const float*)d_in[2];
  const float* y_init = (const float*)d_in[3];
  const float* W_up   = (const float*)d_in[4];
  const float* b_up   = (const float*)d_in[5];
  const float* W_down = (const float*)d_in[6];
  const float* b_down = (const float*)d_in[7];
  const float* ln_w   = (const float*)d_in[8];
  const float* ln_b   = (const float*)d_in[9];
  const float* W_comb = (const float*)d_in[10];
  const float* b_comb = (const float*)d_in[11];
  const float* W_yt   = (const float*)d_in[12];
  const float* b_yt   = (const float*)d_in[13];
  const float* W_head = (const float*)d_in[14];
  const float* b_head = (const float*)d_in[15];

  char* ws = (char*)d_ws;
  h16* winP   = (h16*)(ws + WIN_OFF);
  h16* wupP   = (h16*)(ws + WUP_OFF);
  h16* wdnP   = (h16*)(ws + WDN_OFF);
  h16* wcombP = (h16*)(ws + WCOMB_OFF);
  h16* wytP   = (h16*)(ws + WYT_OFF);
  h16* wheadP = (h16*)(ws + WHEAD_OFF);
  h16* zy = (ws_size >= (size_t)ZY_OFF + ZY_BYTES) ? (h16*)(ws + ZY_OFF) : (h16*)d_in[0];

  hipFuncSetAttribute((const void*)mega_kernel, hipFuncAttributeMaxDynamicSharedMemorySize,
                      SMEM_MEGA);
  hipFuncSetAttribute((const void*)comb_kernel, hipFuncAttributeMaxDynamicSharedMemorySize,
                      SMEM_COMB);

  // prep: cast + fragment-major blocking of all weights
  {
    int tot;
    tot = 8 * (WIN_CSH / 2);
    prepC_kernel<<<dim3((tot + 255) / 256), dim3(256), 0, stream>>>(W_in, winP, 256, WIN_CSH / 2, tot);
    tot = 32 * (WUP_CSH / 2);
    prepC_kernel<<<dim3((tot + 255) / 256), dim3(256), 0, stream>>>(W_up, wupP, 1024, WUP_CSH / 2, tot);
    tot = 8 * (WCOMB_CSH / 2);
    prepC_kernel<<<dim3((tot + 255) / 256), dim3(256), 0, stream>>>(W_comb, wcombP, 256, WCOMB_CSH / 2, tot);
    tot = 32 * (WDN_CSH / 2);
    prepD_kernel<<<dim3((tot + 255) / 256), dim3(256), 0, stream>>>(W_down, wdnP, tot);
    tot = 8 * (WYT_CSH / 2);
    prepD_kernel<<<dim3((tot + 255) / 256), dim3(256), 0, stream>>>(W_yt, wytP, tot);
    prepH_kernel<<<dim3(16), dim3(256), 0, stream>>>(W_head, wheadP);
  }

  for (int h = 0; h < 3; ++h) {
    mega_kernel<<<dim3(512), dim3(512), SMEM_MEGA, stream>>>(
        x, zy, (const char*)winP, (const char*)wupP, (const char*)wdnP, b_in, b_up, b_down,
        ln_w, ln_b, y_init, (h == 0) ? 1 : 0);
    comb_kernel<<<dim3(1024), dim3(512), SMEM_COMB, stream>>>(
        zy, (const char*)wcombP, (const char*)wytP, b_comb, b_yt, y_init, (h == 0) ? 1 : 0);
  }
  head_kernel<<<dim3(1024), dim3(256), SMEM_HEAD, stream>>>(zy, (const char*)wheadP, b_head,
                                                            (float*)d_out);
}